// Round 1
// baseline (121.610 us; speedup 1.0000x reference)
//
#include <hip/hip_runtime.h>

// TripletLoss: B=384, D=1024 fp32, 16 classes, margin=1.
// R7: FUSED single-pass redesign (replaces split-K gram + triplet two-phase).
//   H[a][j] = sq[j] - 2*dot(e_a, e_j)  (sq[a] cancels in the loss).
//   E (384x1024 fp32 = 1.57 MB) fits in every XCD L2 -> per-anchor-block GEMV
//   straight from L2 beats materializing the 4.7 MB split-K P tensor.
//
//   fused_kernel: 128 blocks x 768 threads, 3 anchors/block.
//     - thread pair (2r,2r+1) owns row r: k-interleaved float4 chunks
//       (pair shares 128B lines -> halves address divergence, combine via
//       __shfl_xor(.,1) in-wave, no LDS).
//     - anchor-row loads are wave-uniform -> coalesce to 1 request/wave.
//     - 12 waves = 3/SIMD balanced; dot phase is VALU-issue-saturated:
//       128 chunks x 16 FMA x 2cyc x 3 waves = 12288 cyc ~= 5.1 us floor.
//     - triplet mining in-block: poslist/hist via LDS atomics built BEFORE
//       the dot loop; positives gathered contiguously into Pp[] to break
//       the dependent poslist->Hs LDS address chain.
//     - per-block partial (loss sum, triplet count) -> plain stores to ws
//       (no zero-init needed on poisoned workspace, no ticket, no atomics
//       across blocks -> deterministic).
//   finalize_kernel: 1 block reduces 128 partials -> out[0]=mean, out[1]=count.
//
// NOTE (R5 post-mortem, kept): hipLaunchCooperativeKernel silently no-ops
// under the harness graph capture — do NOT use cooperative launch here.
// NOTE (R7 theory): harness poison fill (~41 us, 268 MB) appears to sit in
// the timed graph; addressable portion is only our ~40 us of kernels.

constexpr int   BN     = 384;
constexpr int   DIM    = 1024;
constexpr int   NCH    = DIM / 4;    // float4 chunks per row (256)
constexpr float MARGIN = 1.0f;
constexpr int   APB    = 3;          // anchors per block
constexpr int   NBLK   = BN / APB;   // 128 blocks
constexpr int   NTHR   = 2 * BN;     // 768 threads = 12 waves (3/SIMD balanced)

__global__ __launch_bounds__(NTHR) void fused_kernel(
    const float* __restrict__ E, const int* __restrict__ labels,
    float* __restrict__ wsum, int* __restrict__ wcnt) {

    __shared__ float Hs[APB][BN];       // H[a_i][j]
    __shared__ float Pp[APB][BN];       // gathered positives (+margin)
    __shared__ int   poslist[APB][BN];
    __shared__ int   npos[APB];
    __shared__ int   hist[16];
    __shared__ float wred[NTHR / 64];

    const int tid = threadIdx.x;
    const int a0  = blockIdx.x * APB;
    const int r   = tid >> 1;           // owned column/row j = r
    const int h   = tid & 1;            // k-interleave phase

    const int la0 = labels[a0 + 0];
    const int la1 = labels[a0 + 1];
    const int la2 = labels[a0 + 2];

    if (tid < 16)  hist[tid] = 0;
    if (tid < APB) npos[tid] = 0;
    __syncthreads();

    // label bookkeeping (depends only on labels -> before the dot loop,
    // its latency hides under the long FMA stream; barrier B1 covers it)
    int lj = 0;
    if (tid < BN) {
        lj = labels[tid];
        atomicAdd(&hist[lj], 1);
        if (lj == la0 && tid > a0 + 0) poslist[0][atomicAdd(&npos[0], 1)] = tid;
        if (lj == la1 && tid > a0 + 1) poslist[1][atomicAdd(&npos[1], 1)] = tid;
        if (lj == la2 && tid > a0 + 2) poslist[2][atomicAdd(&npos[2], 1)] = tid;
    }

    // ---- dot phase: d_i = dot(e_{a0+i}, e_r), qs = dot(e_r, e_r) ----
    const float4* ej = (const float4*)(E + (size_t)r * DIM);
    const float4* e0 = (const float4*)(E + (size_t)(a0 + 0) * DIM);
    const float4* e1 = (const float4*)(E + (size_t)(a0 + 1) * DIM);
    const float4* e2 = (const float4*)(E + (size_t)(a0 + 2) * DIM);

    float d0 = 0.f, d1 = 0.f, d2 = 0.f, qs = 0.f;
#pragma unroll 4
    for (int c = h; c < NCH; c += 2) {
        const float4 v = ej[c];
        const float4 x = e0[c];
        const float4 y = e1[c];
        const float4 z = e2[c];
        qs = fmaf(v.w, v.w, fmaf(v.z, v.z, fmaf(v.y, v.y, fmaf(v.x, v.x, qs))));
        d0 = fmaf(v.w, x.w, fmaf(v.z, x.z, fmaf(v.y, x.y, fmaf(v.x, x.x, d0))));
        d1 = fmaf(v.w, y.w, fmaf(v.z, y.z, fmaf(v.y, y.y, fmaf(v.x, y.x, d1))));
        d2 = fmaf(v.w, z.w, fmaf(v.z, z.z, fmaf(v.y, z.y, fmaf(v.x, z.x, d2))));
    }
    // combine the two k-interleaved halves (lane pairs) in-wave
    d0 += __shfl_xor(d0, 1);
    d1 += __shfl_xor(d1, 1);
    d2 += __shfl_xor(d2, 1);
    qs += __shfl_xor(qs, 1);
    if (h == 0) {
        Hs[0][r] = fmaf(-2.f, d0, qs);
        Hs[1][r] = fmaf(-2.f, d1, qs);
        Hs[2][r] = fmaf(-2.f, d2, qs);
    }
    __syncthreads();   // B1: Hs + hist + poslist all visible

    // gather positives contiguously: Pp[i][k] = H[a_i][p_k] + margin
    // (kills the dependent poslist->Hs address chain in the hot loop)
    if (tid < BN) {
#pragma unroll
        for (int i = 0; i < APB; ++i)
            if (tid < npos[i]) Pp[i][tid] = Hs[i][poslist[i][tid]] + MARGIN;
    }
    __syncthreads();   // B2

    // ---- triplet phase: thread j accumulates over positives if j is a negative ----
    float ls = 0.f;
    if (tid < BN) {
        const int las[APB] = {la0, la1, la2};
#pragma unroll
        for (int i = 0; i < APB; ++i) {
            if (lj != las[i]) {
                const float hn = Hs[i][tid];
                const int   np = npos[i];
                for (int k = 0; k < np; ++k) {
                    const float v = Pp[i][k] - hn;   // broadcast LDS read
                    ls += (v > 0.f) ? v : 0.f;
                }
            }
        }
    }

    // ---- block reduction ----
#pragma unroll
    for (int off = 32; off; off >>= 1) ls += __shfl_down(ls, off);
    if ((tid & 63) == 0) wred[tid >> 6] = ls;
    __syncthreads();   // B3
    if (tid == 0) {
        float s = 0.f;
#pragma unroll
        for (int w = 0; w < NTHR / 64; ++w) s += wred[w];
        const int c = npos[0] * (BN - hist[la0]) +
                      npos[1] * (BN - hist[la1]) +
                      npos[2] * (BN - hist[la2]);
        wsum[blockIdx.x] = s;
        wcnt[blockIdx.x] = c;
    }
}

__global__ __launch_bounds__(NBLK) void finalize_kernel(
    const float* __restrict__ wsum, const int* __restrict__ wcnt,
    float* __restrict__ out) {
    __shared__ float fs[NBLK / 64];
    __shared__ int   fc[NBLK / 64];
    const int t = threadIdx.x;
    float s = wsum[t];
    int   c = wcnt[t];
#pragma unroll
    for (int off = 32; off; off >>= 1) {
        s += __shfl_down(s, off);
        c += __shfl_down(c, off);
    }
    if ((t & 63) == 0) { fs[t >> 6] = s; fc[t >> 6] = c; }
    __syncthreads();
    if (t == 0) {
        float tot = 0.f;
        int   cnt = 0;
#pragma unroll
        for (int w = 0; w < NBLK / 64; ++w) { tot += fs[w]; cnt += fc[w]; }
        out[0] = (cnt > 0) ? tot / (float)cnt : 0.f;
        out[1] = (float)cnt;
    }
}

extern "C" void kernel_launch(void* const* d_in, const int* in_sizes, int n_in,
                              void* d_out, int out_size, void* d_ws, size_t ws_size,
                              hipStream_t stream) {
    const float* E      = (const float*)d_in[0];
    const int*   labels = (const int*)d_in[1];
    float*       out    = (float*)d_out;

    float* wsum = (float*)d_ws;
    int*   wcnt = (int*)((char*)d_ws + (size_t)NBLK * sizeof(float));

    fused_kernel<<<NBLK, NTHR, 0, stream>>>(E, labels, wsum, wcnt);
    finalize_kernel<<<1, NBLK, 0, stream>>>(wsum, wcnt, out);
}

// Round 2
// 82.803 us; speedup vs baseline: 1.4687x; 1.4687x over previous
//
#include <hip/hip_runtime.h>

// TripletLoss: B=384, D=1024 fp32, 16 classes, margin=1.
// R8: two-phase, re-geometried for the LATENCY regime (R7 post-mortem:
// fused design capped grid at 128 blocks -> half GPU idle, VALUBusy 9%).
//
//   gram: Z=16 split-K. 36 tiles (64x64, 4x4 reg block) x 16 = 576 blocks
//         (2.25/CU, 9 waves/CU vs R6's 1.125/CU). KC=64 -> ONE staging
//         phase (8 float4 loads/thread), ONE barrier, 64-k fully-unrolled
//         FMA loop. K-major LDS, XOR-16 swizzle (R6-proven conflict-free).
//         L2 traffic 576x32KB = 18 MB (~0.5us at L2 BW). VALU floor 1.9us.
//   triplet: 384 blocks x 384 threads (1 thread = 1 column, 9 waves/CU).
//         32 independent coalesced scalar loads/thread (16 z-partials of
//         G + 16 of sq), Hrow = s - 2g in-register; positives gathered to
//         Pp[] (broadcast reads in hot loop); ticket last-block finalize.
//
// NOTE (R5 post-mortem, kept): hipLaunchCooperativeKernel silently no-ops
// under the harness graph capture — do NOT use cooperative launch here.
// NOTE (R7): harness poison fill (~41us, 268MB ws) sits in the timed graph;
// it is the floor. Target = fill + ~10us of kernels.

constexpr int   BN     = 384;
constexpr int   DIM    = 1024;
constexpr float MARGIN = 1.0f;
constexpr int   Z      = 16;          // split-K factor
constexpr int   KC     = DIM / Z;     // 64 K per block
constexpr int   LDK    = 68;          // K-major LDS row stride (floats)

// ---------------------------------------------------------------- gram
// grid 36*Z, block 256 (16x16 threads, 4x4 micro-tile -> 64x64 tile).
// Thread t stages row r=t>>2, k-16-group kq=t&3 (4 float4 per matrix).
// LDS element (k,row) at [k*LDK + (row ^ (((k>>4)&3)<<4))].
__global__ __launch_bounds__(256) void gram_kernel(
    const float* __restrict__ E, float* __restrict__ P,
    float* __restrict__ sqpart, float* __restrict__ total,
    int* __restrict__ cnt, int* __restrict__ ticket) {
    __shared__ float Ast[KC * LDK];
    __shared__ float Bst[KC * LDK];
    const int t    = threadIdx.x;
    const int tile = blockIdx.x % 36;
    const int z    = blockIdx.x / 36;
    const int ti   = tile / 6, tj = tile % 6;
    const int i0   = ti * 64, j0 = tj * 64;

    if (blockIdx.x == 0 && t == 0) { *total = 0.f; *cnt = 0; *ticket = 0; }

    const int r  = t >> 2;              // 0..63 staged row
    const int kq = t & 3;               // 0..3  k-16-group
    const int rs = r ^ (kq << 4);       // swizzled LDS row

    const float* Ab = E + (size_t)(i0 + r) * DIM + z * KC + kq * 16;
    const float* Bb = E + (size_t)(j0 + r) * DIM + z * KC + kq * 16;

    float4 a[4], b[4];
#pragma unroll
    for (int q = 0; q < 4; ++q) {
        a[q] = *(const float4*)(Ab + 4 * q);
        b[q] = *(const float4*)(Bb + 4 * q);
    }
#pragma unroll
    for (int q = 0; q < 4; ++q) {
        const int kb = kq * 16 + 4 * q;
        Ast[(kb + 0) * LDK + rs] = a[q].x; Ast[(kb + 1) * LDK + rs] = a[q].y;
        Ast[(kb + 2) * LDK + rs] = a[q].z; Ast[(kb + 3) * LDK + rs] = a[q].w;
        Bst[(kb + 0) * LDK + rs] = b[q].x; Bst[(kb + 1) * LDK + rs] = b[q].y;
        Bst[(kb + 2) * LDK + rs] = b[q].z; Bst[(kb + 3) * LDK + rs] = b[q].w;
    }
    __syncthreads();

    const int tx = t & 15, ty = t >> 4;
    float acc[4][4] = {};
#pragma unroll
    for (int kk = 0; kk < KC; ++kk) {
        const int sw = ((kk >> 4) & 3) << 4;
        const float4 av = *(const float4*)&Ast[kk * LDK + ((4 * ty) ^ sw)];
        const float4 bv = *(const float4*)&Bst[kk * LDK + ((4 * tx) ^ sw)];
        const float aa[4] = {av.x, av.y, av.z, av.w};
        const float bb[4] = {bv.x, bv.y, bv.z, bv.w};
#pragma unroll
        for (int i2 = 0; i2 < 4; ++i2)
#pragma unroll
            for (int j2 = 0; j2 < 4; ++j2)
                acc[i2][j2] = fmaf(aa[i2], bb[j2], acc[i2][j2]);
    }

    const size_t rowstride = (size_t)Z * BN;
#pragma unroll
    for (int i2 = 0; i2 < 4; ++i2) {
        *(float4*)&P[(size_t)(i0 + 4 * ty + i2) * rowstride + (size_t)z * BN + (j0 + 4 * tx)] =
            make_float4(acc[i2][0], acc[i2][1], acc[i2][2], acc[i2][3]);
    }
    if (ti == tj && tx == ty) {         // diagonal -> sq partials
#pragma unroll
        for (int i2 = 0; i2 < 4; ++i2)
            sqpart[z * BN + (i0 + 4 * ty + i2)] = acc[i2][i2];
    }
}

// ---------------------------------------------------------------- triplet + finalize
// 384 blocks x 384 threads; thread tid owns column tid for anchor a=blockIdx.
template <int NZ>
__global__ __launch_bounds__(BN) void triplet_kernel(
    const float* __restrict__ P, const float* __restrict__ sqpart,
    const int* __restrict__ labels, float* __restrict__ total,
    int* __restrict__ cnt, int* __restrict__ ticket, float* __restrict__ out) {
    __shared__ float Hrow[BN];
    __shared__ float Pp[BN];
    __shared__ int   poslist[BN];
    __shared__ int   npos_s;
    __shared__ int   hist[16];
    __shared__ float wred[BN / 64];
    const int a   = blockIdx.x;
    const int tid = threadIdx.x;

    if (tid == 0)  npos_s = 0;
    if (tid < 16)  hist[tid] = 0;
    __syncthreads();

    const int lj = labels[tid];
    const int la = labels[a];           // wave-uniform
    atomicAdd(&hist[lj], 1);
    if (lj == la && tid > a) poslist[atomicAdd(&npos_s, 1)] = tid;

    // 2*NZ fully independent coalesced scalar loads -> deep MLP
    float g = 0.f, s = 0.f;
    const float* Pa = P + (size_t)a * ((size_t)NZ * BN) + tid;
#pragma unroll
    for (int zz = 0; zz < NZ; ++zz) {
        g += Pa[zz * BN];
        s += sqpart[zz * BN + tid];
    }
    const float hn = fmaf(-2.f, g, s);  // H[a][tid]
    Hrow[tid] = hn;
    __syncthreads();                    // Hrow + poslist + hist visible

    const int np = npos_s;
    if (tid < np) Pp[tid] = Hrow[poslist[tid]] + MARGIN;
    __syncthreads();

    float ls = 0.f;
    if (lj != la) {                     // this column is a negative
        for (int k = 0; k < np; ++k) {
            const float v = Pp[k] - hn; // broadcast LDS read
            ls += (v > 0.f) ? v : 0.f;
        }
    }

#pragma unroll
    for (int off = 32; off; off >>= 1) ls += __shfl_down(ls, off);
    if ((tid & 63) == 0) wred[tid >> 6] = ls;
    __syncthreads();
    if (tid == 0) {
        float sum = 0.f;
#pragma unroll
        for (int w = 0; w < BN / 64; ++w) sum += wred[w];
        const int nneg = BN - hist[la];
        if (sum != 0.f) atomicAdd(total, sum);
        if (np)         atomicAdd(cnt, np * nneg);
        __threadfence();
        const int done = atomicAdd(ticket, 1);
        if (done == (int)gridDim.x - 1) {   // last block: finalize
            const float tot = atomicAdd(total, 0.0f);
            const int   c   = atomicAdd(cnt, 0);
            out[0] = (c > 0) ? tot / (float)c : 0.f;
            out[1] = (float)c;
        }
    }
}

extern "C" void kernel_launch(void* const* d_in, const int* in_sizes, int n_in,
                              void* d_out, int out_size, void* d_ws, size_t ws_size,
                              hipStream_t stream) {
    const float* E      = (const float*)d_in[0];
    const int*   labels = (const int*)d_in[1];
    float*       out    = (float*)d_out;

    char*  ws     = (char*)d_ws;
    float* P      = (float*)ws;                                         // BN x (Z*BN)
    float* sqpart = (float*)(ws + (size_t)BN * Z * BN * 4);             // Z x BN
    float* total  = (float*)(ws + (size_t)BN * Z * BN * 4 + (size_t)Z * BN * 4);
    int*   cnt    = (int*)(total + 1);
    int*   ticket = (int*)(total + 2);

    gram_kernel<<<36 * Z, 256, 0, stream>>>(E, P, sqpart, total, cnt, ticket);
    triplet_kernel<Z><<<BN, BN, 0, stream>>>(P, sqpart, labels, total, cnt, ticket, out);
}